// Round 6
// baseline (233.722 us; speedup 1.0000x reference)
//
#include <hip/hip_runtime.h>
#include <hip/hip_bf16.h>

// Problem constants
#define B_ 4
#define S_ 2048
#define D_ 128
#define H_ 8

typedef __attribute__((ext_vector_type(8))) short bf16x8;
typedef __attribute__((ext_vector_type(4))) float f32x4;

__device__ __forceinline__ short f2bf(float f) {
  union { float f; unsigned u; } v; v.f = f;
  unsigned u = v.u;
  unsigned r = (u + 0x7FFFu + ((u >> 16) & 1u)) >> 16;
  return (short)r;
}

// pack 4 fp32 -> 4 bf16 (RNE) as short4
__device__ __forceinline__ short4 pack4(f32x4 p) {
  union { __hip_bfloat162 h2[2]; short4 s4; } u;
  u.h2[0] = __float22bfloat162_rn(make_float2(p[0], p[1]));
  u.h2[1] = __float22bfloat162_rn(make_float2(p[2], p[3]));
  return u.s4;
}

// async global->LDS DMA, 16 B per lane. LDS dest = wave-uniform base + lane*16.
__device__ __forceinline__ void dma16(const short* g, short* l) {
  __builtin_amdgcn_global_load_lds(
      (const __attribute__((address_space(1))) unsigned int*)g,
      (__attribute__((address_space(3))) unsigned int*)l, 16, 0, 0);
}

// prep: transpose+convert W (128,1024) fp32 -> Wt (1024,128) bf16, x3 weights.
// (q/k/v fp32->bf16 conversion is folded into proj3's A-staging.)
__global__ __launch_bounds__(256) void prep(
    const float* __restrict__ WQ, const float* __restrict__ WK, const float* __restrict__ WV,
    short* __restrict__ TQ, short* __restrict__ TK, short* __restrict__ TV) {
  __shared__ float tile[64][65];
  int bw = blockIdx.x >> 5;
  int tl = blockIdx.x & 31;
  int n0 = (tl & 15) * 64, k0 = (tl >> 4) * 64;
  const float* W = (bw == 0) ? WQ : (bw == 1) ? WK : WV;
  short* Wt = (bw == 0) ? TQ : (bw == 1) ? TK : TV;
#pragma unroll
  for (int i = 0; i < 16; ++i) {
    int cix = threadIdx.x + 256 * i;
    int rr = cix >> 6, cc = cix & 63;
    tile[rr][cc] = W[(k0 + rr) * 1024 + n0 + cc];
  }
  __syncthreads();
#pragma unroll
  for (int i = 0; i < 16; ++i) {
    int cix = threadIdx.x + 256 * i;
    int rr = cix >> 6, cc = cix & 63;
    Wt[(n0 + rr) * 128 + k0 + cc] = f2bf(tile[cc][rr]);
  }
}

// ---------------------------------------------------------------------------
// Tiled projection: block = 128(M:s) x 128(N:h*128+d) output tile, K=128.
// A-staging reads the ORIGINAL fp32 input, converts (RNE) and ds_write_b128's
// into the fragment-order LDS image. B-staging: global_load_lds from Wt.
// WA=1 (Q/K): out[b,h,s,d] row-major, short4 stores.
// WA=0 (V):   out = fragment-linear image VF[bh][kb][F][lane][e]:
//   element (key, d):  kb = key>>6, F = (d>>4)*2 + ((key>>5)&1),
//   within-frag short offset = ((key>>3)&3)*128 + (d&15)*8 + (key&7).
// ---------------------------------------------------------------------------
template <int WA>
__device__ __forceinline__ void proj_tile(const float* __restrict__ X,
                                          const short* __restrict__ Wt,
                                          const float* __restrict__ bias,
                                          short* __restrict__ out,
                                          int mtile, int ntile,
                                          short* sA, short* sB) {
  int tid = threadIdx.x;
  int lane = tid & 63, w = tid >> 6;
  int l15 = lane & 15, l4 = lane >> 4;
  int m0 = mtile * 128, n0 = ntile * 128;

  // B frags via DMA (issue first: async, needed at same barrier)
#pragma unroll
  for (int j = 0; j < 8; ++j) {
    int f = w * 8 + j;
    const short* src = Wt + (n0 + (f >> 2) * 16 + l15) * 128 + (f & 3) * 32 + l4 * 8;
    dma16(src, sB + f * 512);
  }
  // A frags: fp32 load -> cvt -> ds_write (fragment-order image, same as DMA'd)
#pragma unroll
  for (int j = 0; j < 8; ++j) {
    int f = w * 8 + j;
    const float* src = X + (size_t)(m0 + (f >> 2) * 16 + l15) * 128 + (f & 3) * 32 + l4 * 8;
    float4 v0 = *(const float4*)src;
    float4 v1 = *(const float4*)(src + 4);
    union { struct { short4 lo, hi; } s; bf16x8 v; } u;
    u.s.lo = pack4((f32x4){v0.x, v0.y, v0.z, v0.w});
    u.s.hi = pack4((f32x4){v1.x, v1.y, v1.z, v1.w});
    *(bf16x8*)(sA + f * 512 + lane * 8) = u.v;
  }
  __syncthreads();  // drains vmcnt (B DMA) + lgkm (A writes)

  int wr = w >> 1, wc = w & 1;  // wave -> 64x64 quadrant
  f32x4 acc[4][4];
#pragma unroll
  for (int mi = 0; mi < 4; ++mi)
#pragma unroll
    for (int ni = 0; ni < 4; ++ni) acc[mi][ni] = (f32x4){0.f, 0.f, 0.f, 0.f};

#pragma unroll
  for (int mi = 0; mi < 4; ++mi) {
    bf16x8 a[4];
#pragma unroll
    for (int st = 0; st < 4; ++st)
      a[st] = *(const bf16x8*)(sA + ((wr * 4 + mi) * 4 + st) * 512 + lane * 8);
#pragma unroll
    for (int ni = 0; ni < 4; ++ni) {
#pragma unroll
      for (int st = 0; st < 4; ++st) {
        bf16x8 b = *(const bf16x8*)(sB + ((wc * 4 + ni) * 4 + st) * 512 + lane * 8);
        if (WA)
          acc[mi][ni] = __builtin_amdgcn_mfma_f32_16x16x32_bf16(b, a[st], acc[mi][ni], 0, 0, 0);
        else
          acc[mi][ni] = __builtin_amdgcn_mfma_f32_16x16x32_bf16(a[st], b, acc[mi][ni], 0, 0, 0);
      }
    }
  }

  if (WA) {
    // C rows = n (l4*4+r), cols = s (l15). h = ntile.
#pragma unroll
    for (int mi = 0; mi < 4; ++mi) {
      int sg = m0 + wr * 64 + mi * 16 + l15;
      int bb = sg >> 11, s = sg & 2047;
      short* orow = out + ((size_t)(bb * H_ + ntile) * S_ + s) * D_;
#pragma unroll
      for (int ni = 0; ni < 4; ++ni) {
        int d0 = wc * 64 + ni * 16 + l4 * 4;
        float4 bv = *(const float4*)(bias + n0 + d0);
        f32x4 t = acc[mi][ni];
        t[0] += bv.x; t[1] += bv.y; t[2] += bv.z; t[3] += bv.w;
        *(short4*)(orow + d0) = pack4(t);
      }
    }
  } else {
    // C rows = s/key (l4*4+r), cols = n/d (l15). Fragment-linear store.
#pragma unroll
    for (int ni = 0; ni < 4; ++ni) {
      int d = wc * 64 + ni * 16 + l15;
      float bvs = bias[n0 + d];
#pragma unroll
      for (int mi = 0; mi < 4; ++mi) {
        int sg0 = m0 + wr * 64 + mi * 16 + l4 * 4;
        int bb = sg0 >> 11, s0 = sg0 & 2047;
        f32x4 t = acc[mi][ni];
        t[0] += bvs; t[1] += bvs; t[2] += bvs; t[3] += bvs;
        size_t off = (size_t)(bb * H_ + ntile) * (S_ * D_)
                   + (size_t)(s0 >> 6) * 8192
                   + (size_t)((d >> 4) * 2 + ((s0 >> 5) & 1)) * 512
                   + ((s0 >> 3) & 3) * 128 + (d & 15) * 8
                   + (s0 & 7);
        *(short4*)(out + off) = pack4(t);
      }
    }
  }
}

// 1536 blocks = 3 projs x 64 m-tiles x 8 n-tiles, n fastest, XCD chunk-swizzled.
__global__ __launch_bounds__(256, 2) void proj3(
    const float* __restrict__ xq, const float* __restrict__ xk, const float* __restrict__ xv,
    const short* __restrict__ wtq, const short* __restrict__ wtk, const short* __restrict__ wtv,
    const float* __restrict__ bQ, const float* __restrict__ bK, const float* __restrict__ bV,
    short* __restrict__ Qp, short* __restrict__ Kp, short* __restrict__ Vf) {
  __shared__ short sA[16384], sB[16384];
  int work = (blockIdx.x & 7) * 192 + (blockIdx.x >> 3);
  int which = work >> 9;
  int t = work & 511;
  int mtile = t >> 3, ntile = t & 7;
  if (which == 0)      proj_tile<1>(xq, wtq, bQ, Qp, mtile, ntile, sA, sB);
  else if (which == 1) proj_tile<1>(xk, wtk, bK, Kp, mtile, ntile, sA, sB);
  else                 proj_tile<0>(xv, wtv, bV, Vf, mtile, ntile, sA, sB);
}

// Flash-style attention with |score| softmax, NO max tracking.
// SOFTWARE-PIPELINED: each body computes QK(t+1) + PV(t) back-to-back on the
// matrix pipe; softmax(t+1) resolves a whole barrier + QK-cluster later.
#define BN 64
#define PSTR 72  // P row stride (shorts)

#define KDMA(BUF, T)                                                           \
  {                                                                            \
    const short* kgs = kg + (T) * BN * D_;                                     \
    short* kl = (BUF) + (w * 4) * 512;                                         \
    dma16(kgs, kl);                                                            \
    dma16(kgs + 32, kl + 512);                                                 \
    dma16(kgs + 64, kl + 1024);                                                \
    dma16(kgs + 96, kl + 1536);                                                \
  }

#define QK_CLUSTER(KB)                                                         \
  _Pragma("unroll") for (int mt = 0; mt < 4; ++mt) {                           \
    s0[mt] = (f32x4){0.f, 0.f, 0.f, 0.f};                                      \
    s1[mt] = (f32x4){0.f, 0.f, 0.f, 0.f};                                      \
    _Pragma("unroll") for (int st = 0; st < 4; ++st) {                         \
      bf16x8 bk = *(const bf16x8*)((KB) + (mt * 4 + st) * 512 + lane * 8);     \
      s0[mt] = __builtin_amdgcn_mfma_f32_16x16x32_bf16(bk, aq[0][st], s0[mt], 0, 0, 0); \
      s1[mt] = __builtin_amdgcn_mfma_f32_16x16x32_bf16(bk, aq[1][st], s1[mt], 0, 0, 0); \
    }                                                                          \
  }

#define SM_CLUSTER()                                                           \
  _Pragma("unroll") for (int mt = 0; mt < 4; ++mt) {                           \
    _Pragma("unroll") for (int r = 0; r < 4; ++r) {                            \
      float p = __builtin_amdgcn_exp2f(fabsf(s0[mt][r]) * SC2);                \
      ls0 += p;                                                                \
      s0[mt][r] = p;                                                           \
    }                                                                          \
    *(short4*)(pw + l15 * PSTR + mt * 16 + l4 * 4) = pack4(s0[mt]);            \
  }                                                                            \
  ap0[0] = *(const bf16x8*)(pw + l15 * PSTR + l4 * 8);                         \
  ap0[1] = *(const bf16x8*)(pw + l15 * PSTR + 32 + l4 * 8);                    \
  _Pragma("unroll") for (int mt = 0; mt < 4; ++mt) {                           \
    _Pragma("unroll") for (int r = 0; r < 4; ++r) {                            \
      float p = __builtin_amdgcn_exp2f(fabsf(s1[mt][r]) * SC2);                \
      ls1 += p;                                                                \
      s1[mt][r] = p;                                                           \
    }                                                                          \
    *(short4*)(pw + l15 * PSTR + mt * 16 + l4 * 4) = pack4(s1[mt]);            \
  }                                                                            \
  ap1[0] = *(const bf16x8*)(pw + l15 * PSTR + l4 * 8);                         \
  ap1[1] = *(const bf16x8*)(pw + l15 * PSTR + 32 + l4 * 8);

#define PV_CLUSTER()                                                           \
  _Pragma("unroll") for (int t8 = 0; t8 < 8; ++t8) {                           \
    _Pragma("unroll") for (int kst = 0; kst < 2; ++kst) {                      \
      o0[t8] = __builtin_amdgcn_mfma_f32_16x16x32_bf16(ap0[kst], bv[t8 * 2 + kst], o0[t8], 0, 0, 0); \
      o1[t8] = __builtin_amdgcn_mfma_f32_16x16x32_bf16(ap1[kst], bv[t8 * 2 + kst], o1[t8], 0, 0, 0); \
    }                                                                          \
  }

__global__ __launch_bounds__(256, 2) void attn(const short* __restrict__ Qp,
                                               const short* __restrict__ Kp,
                                               const short* __restrict__ Vf,
                                               float* __restrict__ out) {
  __shared__ short sK0[8192], sK1[8192];  // 16 KB each, fragment-order
  __shared__ short sP[4 * 16 * PSTR];     // per-wave P region

  int tid = threadIdx.x;
  int lane = tid & 63, w = tid >> 6;
  // XCD chunk-swizzle (bijective, 512 blocks)
  int swz = (blockIdx.x & 7) * 64 + (blockIdx.x >> 3);
  int qt = swz & 15; // 16 q-tiles of 128
  int bh = swz >> 4; // 0..31
  int q0 = qt * 128;
  int l15 = lane & 15, l4 = lane >> 4;

  const short* Qbase = Qp + (size_t)bh * S_ * D_;
  const short* Kbase = Kp + (size_t)bh * S_ * D_;
  const short* vfb = Vf + (size_t)bh * S_ * D_ + lane * 8;  // frag-linear V

  // K DMA source address (fragment-order image)
  const short* kg = Kbase + (w * 16 + l15) * D_ + l4 * 8;

  KDMA(sK0, 0);  // stage K tile 0

  // Q B-fragments for two 16-q groups (q = q0 + w*32 + g*16 + l15)
  bf16x8 aq[2][4];
#pragma unroll
  for (int g = 0; g < 2; ++g)
#pragma unroll
    for (int st = 0; st < 4; ++st)
      aq[g][st] = *(const bf16x8*)(Qbase + (q0 + w * 32 + g * 16 + l15) * D_ + l4 * 8 + 32 * st);

  f32x4 o0[8], o1[8];
#pragma unroll
  for (int t = 0; t < 8; ++t) {
    o0[t] = (f32x4){0.f, 0.f, 0.f, 0.f};
    o1[t] = (f32x4){0.f, 0.f, 0.f, 0.f};
  }
  float ls0 = 0.f, ls1 = 0.f;

  const float SC2 = 0.127530637f; // log2(e)/sqrt(128)
  short* pw = sP + w * 16 * PSTR;

  __syncthreads(); // K0 ready

  f32x4 s0[4], s1[4];
  bf16x8 ap0[2], ap1[2];

  // pre-body: stage K1; QK_0 + sm_0 -> ap regs
  KDMA(sK1, 1);
  QK_CLUSTER(sK0);
  SM_CLUSTER();
  __syncthreads(); // K1 ready (drains K1 DMA)

  for (int t = 0; t < 31; ++t) {
    // V-frags for tile t: contiguous 1 KB wave-loads, issued BEFORE K-DMA
    bf16x8 bv[16];
#pragma unroll
    for (int f = 0; f < 16; ++f)
      bv[f] = *(const bf16x8*)(vfb + t * 8192 + f * 512);
    __builtin_amdgcn_sched_barrier(0);
    if (t < 30) {
      short* kdst = (t & 1) ? sK1 : sK0;  // buf[(t+2)&1]
      KDMA(kdst, t + 2);
    }
    const short* kb = (t & 1) ? sK0 : sK1;  // buf[(t+1)&1]
    __builtin_amdgcn_s_setprio(1);
    QK_CLUSTER(kb);   // s0,s1 <- tile t+1
    PV_CLUSTER();     // o += P_t V_t  (ap from previous body's SM)
    __builtin_amdgcn_s_setprio(0);
    SM_CLUSTER();     // ap <- tile t+1 (resolves before next body's PV)
    __syncthreads();  // drains K-DMA(t+2); guards K buffer reuse
  }

  // epilogue: PV_31
  {
    bf16x8 bv[16];
#pragma unroll
    for (int f = 0; f < 16; ++f)
      bv[f] = *(const bf16x8*)(vfb + 31 * 8192 + f * 512);
    PV_CLUSTER();
  }

  // final softmax denominators: per-lane partial sums -> quad reduce
  ls0 += __shfl_xor(ls0, 16);
  ls0 += __shfl_xor(ls0, 32);
  ls1 += __shfl_xor(ls1, 16);
  ls1 += __shfl_xor(ls1, 32);
  float inv0[4], inv1[4];
#pragma unroll
  for (int r = 0; r < 4; ++r) {
    inv0[r] = 1.f / __shfl(ls0, l4 * 4 + r);
    inv1[r] = 1.f / __shfl(ls1, l4 * 4 + r);
  }

  // epilogue: out[b, q, h*128 + dv] fp32
  int bb = bh >> 3, h = bh & 7;
#pragma unroll
  for (int t = 0; t < 8; ++t) {
#pragma unroll
    for (int r = 0; r < 4; ++r) {
      int qA = q0 + w * 32 + l4 * 4 + r;
      int qB = qA + 16;
      out[((size_t)(bb * S_ + qA)) * (H_ * D_) + h * D_ + t * 16 + l15] = o0[t][r] * inv0[r];
      out[((size_t)(bb * S_ + qB)) * (H_ * D_) + h * D_ + t * 16 + l15] = o1[t][r] * inv1[r];
    }
  }
}

extern "C" void kernel_launch(void* const* d_in, const int* in_sizes, int n_in,
                              void* d_out, int out_size, void* d_ws, size_t ws_size,
                              hipStream_t stream) {
  (void)in_sizes; (void)n_in; (void)out_size; (void)ws_size;
  const float* q  = (const float*)d_in[0];
  const float* k  = (const float*)d_in[1];
  const float* v  = (const float*)d_in[2];
  const float* WQ = (const float*)d_in[3];
  const float* bQ = (const float*)d_in[4];
  const float* WK = (const float*)d_in[5];
  const float* bK = (const float*)d_in[6];
  const float* WV = (const float*)d_in[7];
  const float* bV = (const float*)d_in[8];

  const int NW = D_ * H_ * D_;      // 131072 per weight
  const int NP = B_ * H_ * S_ * D_; // 8388608 per projected tensor

  short* ws  = (short*)d_ws;
  short* wtq = ws;
  short* wtk = wtq + NW;
  short* wtv = wtk + NW;
  short* Qp  = wtv + NW;
  short* Kp  = Qp + NP;
  short* Vf  = Kp + NP;

  prep<<<96, 256, 0, stream>>>(WQ, WK, WV, wtq, wtk, wtv);

  // DIAGNOSTIC ROUND: proj3 launched TWICE (idempotent — identical outputs).
  // proj3_duration = (total_new − attn_new) − 101.8 µs   [r5 residual]
  // Story A (proj3 ~90 µs): total ≈ 285.  Story B (proj3 ~12 µs): total ≈ 208.
  proj3<<<1536, 256, 0, stream>>>(q, k, v, wtq, wtk, wtv, bQ, bK, bV, Qp, Kp, Vf);
  proj3<<<1536, 256, 0, stream>>>(q, k, v, wtq, wtk, wtv, bQ, bK, bV, Qp, Kp, Vf);

  attn<<<512, 256, 0, stream>>>(Qp, Kp, Vf, (float*)d_out);
}

// Round 7
// 194.785 us; speedup vs baseline: 1.1999x; 1.1999x over previous
//
#include <hip/hip_runtime.h>
#include <hip/hip_bf16.h>

// Problem constants
#define B_ 4
#define S_ 2048
#define D_ 128
#define H_ 8

typedef __attribute__((ext_vector_type(8))) short bf16x8;
typedef __attribute__((ext_vector_type(4))) float f32x4;

__device__ __forceinline__ short f2bf(float f) {
  union { float f; unsigned u; } v; v.f = f;
  unsigned u = v.u;
  unsigned r = (u + 0x7FFFu + ((u >> 16) & 1u)) >> 16;
  return (short)r;
}

// pack 4 fp32 -> 4 bf16 (RNE) as short4
__device__ __forceinline__ short4 pack4(f32x4 p) {
  union { __hip_bfloat162 h2[2]; short4 s4; } u;
  u.h2[0] = __float22bfloat162_rn(make_float2(p[0], p[1]));
  u.h2[1] = __float22bfloat162_rn(make_float2(p[2], p[3]));
  return u.s4;
}

// async global->LDS DMA, 16 B per lane. LDS dest = wave-uniform base + lane*16.
__device__ __forceinline__ void dma16(const short* g, short* l) {
  __builtin_amdgcn_global_load_lds(
      (const __attribute__((address_space(1))) unsigned int*)g,
      (__attribute__((address_space(3))) unsigned int*)l, 16, 0, 0);
}

// prep: transpose+convert W (128,1024) fp32 -> Wt (1024,128) bf16, x3 weights.
__global__ __launch_bounds__(256) void prep(
    const float* __restrict__ WQ, const float* __restrict__ WK, const float* __restrict__ WV,
    short* __restrict__ TQ, short* __restrict__ TK, short* __restrict__ TV) {
  __shared__ float tile[64][65];
  int bw = blockIdx.x >> 5;
  int tl = blockIdx.x & 31;
  int n0 = (tl & 15) * 64, k0 = (tl >> 4) * 64;
  const float* W = (bw == 0) ? WQ : (bw == 1) ? WK : WV;
  short* Wt = (bw == 0) ? TQ : (bw == 1) ? TK : TV;
#pragma unroll
  for (int i = 0; i < 16; ++i) {
    int cix = threadIdx.x + 256 * i;
    int rr = cix >> 6, cc = cix & 63;
    tile[rr][cc] = W[(k0 + rr) * 1024 + n0 + cc];
  }
  __syncthreads();
#pragma unroll
  for (int i = 0; i < 16; ++i) {
    int cix = threadIdx.x + 256 * i;
    int rr = cix >> 6, cc = cix & 63;
    Wt[(n0 + rr) * 128 + k0 + cc] = f2bf(tile[cc][rr]);
  }
}

// ---------------------------------------------------------------------------
// Tiled projection: block = 128(M:s) x 128(N:h*128+d) output tile, K=128.
// A-staging: fp32 load -> RNE cvt -> ds_write into fragment-order LDS image.
// B-staging: global_load_lds from pre-transposed bf16 Wt.
// MODE 0 (Q): out[b,h,s,d] row-major, short4 stores.
// MODE 1 (K): fragment-linear image KF[bh][kb][F][lane][e]:
//   element (key,d): kb=key>>6, F=((key>>4)&3)*4+(d>>5),
//   within-frag short offset = ((d>>3)&3)*128 + (key&15)*8 + (d&7).
//   (attn reads frag (mt,st) as key=kt+mt*16+l15, d=st*32+l4*8+e -> 1 KB/wave.)
// MODE 2 (V): fragment-linear image VF[bh][kb][F][lane][e]:
//   element (key,d): kb=key>>6, F=(d>>4)*2+((key>>5)&1),
//   within-frag short offset = ((key>>3)&3)*128 + (d&15)*8 + (key&7).
// ---------------------------------------------------------------------------
template <int MODE>
__device__ __forceinline__ void proj_tile(const float* __restrict__ X,
                                          const short* __restrict__ Wt,
                                          const float* __restrict__ bias,
                                          short* __restrict__ out,
                                          int mtile, int ntile,
                                          short* sA, short* sB) {
  int tid = threadIdx.x;
  int lane = tid & 63, w = tid >> 6;
  int l15 = lane & 15, l4 = lane >> 4;
  int m0 = mtile * 128, n0 = ntile * 128;

  // B frags via DMA (issue first: async, needed at same barrier)
#pragma unroll
  for (int j = 0; j < 8; ++j) {
    int f = w * 8 + j;
    const short* src = Wt + (n0 + (f >> 2) * 16 + l15) * 128 + (f & 3) * 32 + l4 * 8;
    dma16(src, sB + f * 512);
  }
  // A frags: fp32 load -> cvt -> ds_write (fragment-order image)
#pragma unroll
  for (int j = 0; j < 8; ++j) {
    int f = w * 8 + j;
    const float* src = X + (size_t)(m0 + (f >> 2) * 16 + l15) * 128 + (f & 3) * 32 + l4 * 8;
    float4 v0 = *(const float4*)src;
    float4 v1 = *(const float4*)(src + 4);
    union { struct { short4 lo, hi; } s; bf16x8 v; } u;
    u.s.lo = pack4((f32x4){v0.x, v0.y, v0.z, v0.w});
    u.s.hi = pack4((f32x4){v1.x, v1.y, v1.z, v1.w});
    *(bf16x8*)(sA + f * 512 + lane * 8) = u.v;
  }
  __syncthreads();  // drains vmcnt (B DMA) + lgkm (A writes)

  int wr = w >> 1, wc = w & 1;  // wave -> 64x64 quadrant
  f32x4 acc[4][4];
#pragma unroll
  for (int mi = 0; mi < 4; ++mi)
#pragma unroll
    for (int ni = 0; ni < 4; ++ni) acc[mi][ni] = (f32x4){0.f, 0.f, 0.f, 0.f};

#pragma unroll
  for (int mi = 0; mi < 4; ++mi) {
    bf16x8 a[4];
#pragma unroll
    for (int st = 0; st < 4; ++st)
      a[st] = *(const bf16x8*)(sA + ((wr * 4 + mi) * 4 + st) * 512 + lane * 8);
#pragma unroll
    for (int ni = 0; ni < 4; ++ni) {
#pragma unroll
      for (int st = 0; st < 4; ++st) {
        bf16x8 b = *(const bf16x8*)(sB + ((wc * 4 + ni) * 4 + st) * 512 + lane * 8);
        if (MODE <= 1)
          acc[mi][ni] = __builtin_amdgcn_mfma_f32_16x16x32_bf16(b, a[st], acc[mi][ni], 0, 0, 0);
        else
          acc[mi][ni] = __builtin_amdgcn_mfma_f32_16x16x32_bf16(a[st], b, acc[mi][ni], 0, 0, 0);
      }
    }
  }

  if (MODE == 0) {
    // C rows = n (l4*4+r), cols = s (l15). h = ntile. Row-major [b,h,s,d].
#pragma unroll
    for (int mi = 0; mi < 4; ++mi) {
      int sg = m0 + wr * 64 + mi * 16 + l15;
      int bb = sg >> 11, s = sg & 2047;
      short* orow = out + ((size_t)(bb * H_ + ntile) * S_ + s) * D_;
#pragma unroll
      for (int ni = 0; ni < 4; ++ni) {
        int d0 = wc * 64 + ni * 16 + l4 * 4;
        float4 bv = *(const float4*)(bias + n0 + d0);
        f32x4 t = acc[mi][ni];
        t[0] += bv.x; t[1] += bv.y; t[2] += bv.z; t[3] += bv.w;
        *(short4*)(orow + d0) = pack4(t);
      }
    }
  } else if (MODE == 1) {
    // C rows = n/d (l4*4+r), cols = s/key (l15). K fragment-linear store.
    // Lane holds 4 consecutive d (d0%8 in {0,4}) for one key -> short4 over e.
#pragma unroll
    for (int mi = 0; mi < 4; ++mi) {
      int key = m0 + wr * 64 + mi * 16 + l15;
      int bb = key >> 11, k = key & 2047;
      size_t base = (size_t)(bb * H_ + ntile) * (S_ * D_) + (size_t)(k >> 6) * 8192
                  + ((k >> 4) & 3) * 4 * 512 + (k & 15) * 8;
#pragma unroll
      for (int ni = 0; ni < 4; ++ni) {
        int d0 = wc * 64 + ni * 16 + l4 * 4;
        float4 bv = *(const float4*)(bias + n0 + d0);
        f32x4 t = acc[mi][ni];
        t[0] += bv.x; t[1] += bv.y; t[2] += bv.z; t[3] += bv.w;
        size_t off = base + (size_t)(d0 >> 5) * 512 + ((d0 >> 3) & 3) * 128 + (d0 & 7);
        *(short4*)(out + off) = pack4(t);
      }
    }
  } else {
    // C rows = s/key (l4*4+r), cols = n/d (l15). V fragment-linear store.
#pragma unroll
    for (int ni = 0; ni < 4; ++ni) {
      int d = wc * 64 + ni * 16 + l15;
      float bvs = bias[n0 + d];
#pragma unroll
      for (int mi = 0; mi < 4; ++mi) {
        int sg0 = m0 + wr * 64 + mi * 16 + l4 * 4;
        int bb = sg0 >> 11, s0 = sg0 & 2047;
        f32x4 t = acc[mi][ni];
        t[0] += bvs; t[1] += bvs; t[2] += bvs; t[3] += bvs;
        size_t off = (size_t)(bb * H_ + ntile) * (S_ * D_)
                   + (size_t)(s0 >> 6) * 8192
                   + (size_t)((d >> 4) * 2 + ((s0 >> 5) & 1)) * 512
                   + ((s0 >> 3) & 3) * 128 + (d & 15) * 8
                   + (s0 & 7);
        *(short4*)(out + off) = pack4(t);
      }
    }
  }
}

// 1536 blocks = 3 projs x 64 m-tiles x 8 n-tiles, n fastest, XCD chunk-swizzled.
// launch_bounds (256,3): 3 blocks/CU (LDS 96 KB, VGPR cap 170) for latency hiding.
__global__ __launch_bounds__(256, 3) void proj3(
    const float* __restrict__ xq, const float* __restrict__ xk, const float* __restrict__ xv,
    const short* __restrict__ wtq, const short* __restrict__ wtk, const short* __restrict__ wtv,
    const float* __restrict__ bQ, const float* __restrict__ bK, const float* __restrict__ bV,
    short* __restrict__ Qp, short* __restrict__ Kf, short* __restrict__ Vf) {
  __shared__ short sA[16384], sB[16384];
  int work = (blockIdx.x & 7) * 192 + (blockIdx.x >> 3);
  int which = work >> 9;
  int t = work & 511;
  int mtile = t >> 3, ntile = t & 7;
  if (which == 0)      proj_tile<0>(xq, wtq, bQ, Qp, mtile, ntile, sA, sB);
  else if (which == 1) proj_tile<1>(xk, wtk, bK, Kf, mtile, ntile, sA, sB);
  else                 proj_tile<2>(xv, wtv, bV, Vf, mtile, ntile, sA, sB);
}

// Flash-style attention with |score| softmax, NO max tracking.
// BARRIER-FREE: K and V are both read from L2 in fragment-linear layout
// (contiguous 1 KB wave-loads). No shared LDS staging, no __syncthreads() --
// the 8 waves/CU drift into different phases, so one wave's MFMA overlaps
// another's exp2/DS work (m114 mechanism). sP is per-wave private (DS in-order).
// Issue order kf -> bv gives QK a counted vmcnt(16) wait and PV vmcnt(0).
#define PSTR 72  // P row stride (shorts)

#define QK_CLUSTER()                                                           \
  _Pragma("unroll") for (int mt = 0; mt < 4; ++mt) {                           \
    s0[mt] = (f32x4){0.f, 0.f, 0.f, 0.f};                                      \
    s1[mt] = (f32x4){0.f, 0.f, 0.f, 0.f};                                      \
    _Pragma("unroll") for (int st = 0; st < 4; ++st) {                         \
      s0[mt] = __builtin_amdgcn_mfma_f32_16x16x32_bf16(kf[mt * 4 + st], aq[0][st], s0[mt], 0, 0, 0); \
      s1[mt] = __builtin_amdgcn_mfma_f32_16x16x32_bf16(kf[mt * 4 + st], aq[1][st], s1[mt], 0, 0, 0); \
    }                                                                          \
  }

#define SM_CLUSTER()                                                           \
  _Pragma("unroll") for (int mt = 0; mt < 4; ++mt) {                           \
    _Pragma("unroll") for (int r = 0; r < 4; ++r) {                            \
      float p = __builtin_amdgcn_exp2f(fabsf(s0[mt][r]) * SC2);                \
      ls0 += p;                                                                \
      s0[mt][r] = p;                                                           \
    }                                                                          \
    *(short4*)(pw + l15 * PSTR + mt * 16 + l4 * 4) = pack4(s0[mt]);            \
  }                                                                            \
  ap0[0] = *(const bf16x8*)(pw + l15 * PSTR + l4 * 8);                         \
  ap0[1] = *(const bf16x8*)(pw + l15 * PSTR + 32 + l4 * 8);                    \
  _Pragma("unroll") for (int mt = 0; mt < 4; ++mt) {                           \
    _Pragma("unroll") for (int r = 0; r < 4; ++r) {                            \
      float p = __builtin_amdgcn_exp2f(fabsf(s1[mt][r]) * SC2);                \
      ls1 += p;                                                                \
      s1[mt][r] = p;                                                           \
    }                                                                          \
    *(short4*)(pw + l15 * PSTR + mt * 16 + l4 * 4) = pack4(s1[mt]);            \
  }                                                                            \
  ap1[0] = *(const bf16x8*)(pw + l15 * PSTR + l4 * 8);                         \
  ap1[1] = *(const bf16x8*)(pw + l15 * PSTR + 32 + l4 * 8);

#define PV_CLUSTER()                                                           \
  _Pragma("unroll") for (int t8 = 0; t8 < 8; ++t8) {                           \
    _Pragma("unroll") for (int kst = 0; kst < 2; ++kst) {                      \
      o0[t8] = __builtin_amdgcn_mfma_f32_16x16x32_bf16(ap0[kst], bv[t8 * 2 + kst], o0[t8], 0, 0, 0); \
      o1[t8] = __builtin_amdgcn_mfma_f32_16x16x32_bf16(ap1[kst], bv[t8 * 2 + kst], o1[t8], 0, 0, 0); \
    }                                                                          \
  }

__global__ __launch_bounds__(256, 2) void attn(const short* __restrict__ Qp,
                                               const short* __restrict__ Kf,
                                               const short* __restrict__ Vf,
                                               float* __restrict__ out) {
  __shared__ short sP[4 * 16 * PSTR];  // per-wave P region (only LDS in kernel)

  int tid = threadIdx.x;
  int lane = tid & 63, w = tid >> 6;
  // XCD chunk-swizzle (bijective, 512 blocks): 4 (b,h) pairs per XCD -> K/V
  // working set 4 MB = one L2.
  int swz = (blockIdx.x & 7) * 64 + (blockIdx.x >> 3);
  int qt = swz & 15; // 16 q-tiles of 128
  int bh = swz >> 4; // 0..31
  int q0 = qt * 128;
  int l15 = lane & 15, l4 = lane >> 4;

  const short* Qbase = Qp + (size_t)bh * S_ * D_;
  const short* kfb = Kf + (size_t)bh * S_ * D_ + lane * 8;  // frag-linear K
  const short* vfb = Vf + (size_t)bh * S_ * D_ + lane * 8;  // frag-linear V

  // Q B-fragments for two 16-q groups (q = q0 + w*32 + g*16 + l15)
  bf16x8 aq[2][4];
#pragma unroll
  for (int g = 0; g < 2; ++g)
#pragma unroll
    for (int st = 0; st < 4; ++st)
      aq[g][st] = *(const bf16x8*)(Qbase + (q0 + w * 32 + g * 16 + l15) * D_ + l4 * 8 + 32 * st);

  f32x4 o0[8], o1[8];
#pragma unroll
  for (int t = 0; t < 8; ++t) {
    o0[t] = (f32x4){0.f, 0.f, 0.f, 0.f};
    o1[t] = (f32x4){0.f, 0.f, 0.f, 0.f};
  }
  float ls0 = 0.f, ls1 = 0.f;

  const float SC2 = 0.127530637f; // log2(e)/sqrt(128)
  short* pw = sP + w * 16 * PSTR;

  for (int t = 0; t < S_ / 64; ++t) {
    // K-frags then V-frags: 32 contiguous 1 KB wave-loads from L2.
    bf16x8 kf[16];
#pragma unroll
    for (int f = 0; f < 16; ++f)
      kf[f] = *(const bf16x8*)(kfb + t * 8192 + f * 512);
    bf16x8 bv[16];
#pragma unroll
    for (int f = 0; f < 16; ++f)
      bv[f] = *(const bf16x8*)(vfb + t * 8192 + f * 512);
    __builtin_amdgcn_sched_barrier(0);  // pin issue before compute

    f32x4 s0[4], s1[4];
    __builtin_amdgcn_s_setprio(1);
    QK_CLUSTER();   // waits vmcnt(16): K done, V still in flight
    __builtin_amdgcn_s_setprio(0);
    bf16x8 ap0[2], ap1[2];
    SM_CLUSTER();   // trans/VALU + per-wave P round-trip (lgkm only)
    __builtin_amdgcn_s_setprio(1);
    PV_CLUSTER();   // waits vmcnt(0): V done
    __builtin_amdgcn_s_setprio(0);
  }

  // final softmax denominators: per-lane partial sums -> quad reduce
  ls0 += __shfl_xor(ls0, 16);
  ls0 += __shfl_xor(ls0, 32);
  ls1 += __shfl_xor(ls1, 16);
  ls1 += __shfl_xor(ls1, 32);
  float inv0[4], inv1[4];
#pragma unroll
  for (int r = 0; r < 4; ++r) {
    inv0[r] = 1.f / __shfl(ls0, l4 * 4 + r);
    inv1[r] = 1.f / __shfl(ls1, l4 * 4 + r);
  }

  // epilogue: out[b, q, h*128 + dv] fp32
  int bb = bh >> 3, h = bh & 7;
#pragma unroll
  for (int t = 0; t < 8; ++t) {
#pragma unroll
    for (int r = 0; r < 4; ++r) {
      int qA = q0 + w * 32 + l4 * 4 + r;
      int qB = qA + 16;
      out[((size_t)(bb * S_ + qA)) * (H_ * D_) + h * D_ + t * 16 + l15] = o0[t][r] * inv0[r];
      out[((size_t)(bb * S_ + qB)) * (H_ * D_) + h * D_ + t * 16 + l15] = o1[t][r] * inv1[r];
    }
  }
}

extern "C" void kernel_launch(void* const* d_in, const int* in_sizes, int n_in,
                              void* d_out, int out_size, void* d_ws, size_t ws_size,
                              hipStream_t stream) {
  (void)in_sizes; (void)n_in; (void)out_size; (void)ws_size;
  const float* q  = (const float*)d_in[0];
  const float* k  = (const float*)d_in[1];
  const float* v  = (const float*)d_in[2];
  const float* WQ = (const float*)d_in[3];
  const float* bQ = (const float*)d_in[4];
  const float* WK = (const float*)d_in[5];
  const float* bK = (const float*)d_in[6];
  const float* WV = (const float*)d_in[7];
  const float* bV = (const float*)d_in[8];

  const int NW = D_ * H_ * D_;      // 131072 per weight
  const int NP = B_ * H_ * S_ * D_; // 8388608 per projected tensor

  short* ws  = (short*)d_ws;
  short* wtq = ws;
  short* wtk = wtq + NW;
  short* wtv = wtk + NW;
  short* Qp  = wtv + NW;
  short* Kf  = Qp + NP;
  short* Vf  = Kf + NP;

  prep<<<96, 256, 0, stream>>>(WQ, WK, WV, wtq, wtk, wtv);

  proj3<<<1536, 256, 0, stream>>>(q, k, v, wtq, wtk, wtv, bQ, bK, bV, Qp, Kf, Vf);

  attn<<<512, 256, 0, stream>>>(Qp, Kf, Vf, (float*)d_out);
}

// Round 8
// 186.179 us; speedup vs baseline: 1.2554x; 1.0462x over previous
//
#include <hip/hip_runtime.h>
#include <hip/hip_bf16.h>

// Problem constants
#define B_ 4
#define S_ 2048
#define D_ 128
#define H_ 8

typedef __attribute__((ext_vector_type(8))) short bf16x8;
typedef __attribute__((ext_vector_type(4))) float f32x4;

__device__ __forceinline__ short f2bf(float f) {
  union { float f; unsigned u; } v; v.f = f;
  unsigned u = v.u;
  unsigned r = (u + 0x7FFFu + ((u >> 16) & 1u)) >> 16;
  return (short)r;
}

// pack 4 fp32 -> 4 bf16 (RNE) as short4
__device__ __forceinline__ short4 pack4(f32x4 p) {
  union { __hip_bfloat162 h2[2]; short4 s4; } u;
  u.h2[0] = __float22bfloat162_rn(make_float2(p[0], p[1]));
  u.h2[1] = __float22bfloat162_rn(make_float2(p[2], p[3]));
  return u.s4;
}

// async global->LDS DMA, 16 B per lane. LDS dest = wave-uniform base + lane*16.
__device__ __forceinline__ void dma16(const short* g, short* l) {
  __builtin_amdgcn_global_load_lds(
      (const __attribute__((address_space(1))) unsigned int*)g,
      (__attribute__((address_space(3))) unsigned int*)l, 16, 0, 0);
}

// prep: transpose+convert W (128,1024) fp32 -> Wt (1024,128) bf16, x3 weights.
__global__ __launch_bounds__(256) void prep(
    const float* __restrict__ WQ, const float* __restrict__ WK, const float* __restrict__ WV,
    short* __restrict__ TQ, short* __restrict__ TK, short* __restrict__ TV) {
  __shared__ float tile[64][65];
  int bw = blockIdx.x >> 5;
  int tl = blockIdx.x & 31;
  int n0 = (tl & 15) * 64, k0 = (tl >> 4) * 64;
  const float* W = (bw == 0) ? WQ : (bw == 1) ? WK : WV;
  short* Wt = (bw == 0) ? TQ : (bw == 1) ? TK : TV;
#pragma unroll
  for (int i = 0; i < 16; ++i) {
    int cix = threadIdx.x + 256 * i;
    int rr = cix >> 6, cc = cix & 63;
    tile[rr][cc] = W[(k0 + rr) * 1024 + n0 + cc];
  }
  __syncthreads();
#pragma unroll
  for (int i = 0; i < 16; ++i) {
    int cix = threadIdx.x + 256 * i;
    int rr = cix >> 6, cc = cix & 63;
    Wt[(n0 + rr) * 128 + k0 + cc] = f2bf(tile[cc][rr]);
  }
}

// ---------------------------------------------------------------------------
// Tiled projection: block = 128(M:s) x 128(N:h*128+d) output tile, K=128.
// A-staging: fp32 load -> RNE cvt -> ds_write into fragment-order LDS image.
// B-staging: global_load_lds from pre-transposed bf16 Wt.
// MODE 0 (Q): out[b,h,s,d] row-major, short4 stores.
// MODE 1 (K): fragment-linear image KF[bh][kb][F][lane][e]:
//   element (key,d): kb=key>>6, F=((key>>4)&3)*4+(d>>5),
//   within-frag short offset = ((d>>3)&3)*128 + (key&15)*8 + (d&7).
// MODE 2 (V): fragment-linear image VF[bh][kb][F][lane][e]:
//   element (key,d): kb=key>>6, F=(d>>4)*2+((key>>5)&1),
//   within-frag short offset = ((key>>3)&3)*128 + (d&15)*8 + (key&7).
// ---------------------------------------------------------------------------
template <int MODE>
__device__ __forceinline__ void proj_tile(const float* __restrict__ X,
                                          const short* __restrict__ Wt,
                                          const float* __restrict__ bias,
                                          short* __restrict__ out,
                                          int mtile, int ntile,
                                          short* sA, short* sB) {
  int tid = threadIdx.x;
  int lane = tid & 63, w = tid >> 6;
  int l15 = lane & 15, l4 = lane >> 4;
  int m0 = mtile * 128, n0 = ntile * 128;

  // B frags via DMA (issue first: async, needed at same barrier)
#pragma unroll
  for (int j = 0; j < 8; ++j) {
    int f = w * 8 + j;
    const short* src = Wt + (n0 + (f >> 2) * 16 + l15) * 128 + (f & 3) * 32 + l4 * 8;
    dma16(src, sB + f * 512);
  }
  // A frags: fp32 load -> cvt -> ds_write (fragment-order image)
#pragma unroll
  for (int j = 0; j < 8; ++j) {
    int f = w * 8 + j;
    const float* src = X + (size_t)(m0 + (f >> 2) * 16 + l15) * 128 + (f & 3) * 32 + l4 * 8;
    float4 v0 = *(const float4*)src;
    float4 v1 = *(const float4*)(src + 4);
    union { struct { short4 lo, hi; } s; bf16x8 v; } u;
    u.s.lo = pack4((f32x4){v0.x, v0.y, v0.z, v0.w});
    u.s.hi = pack4((f32x4){v1.x, v1.y, v1.z, v1.w});
    *(bf16x8*)(sA + f * 512 + lane * 8) = u.v;
  }
  __syncthreads();  // drains vmcnt (B DMA) + lgkm (A writes)

  int wr = w >> 1, wc = w & 1;  // wave -> 64x64 quadrant
  f32x4 acc[4][4];
#pragma unroll
  for (int mi = 0; mi < 4; ++mi)
#pragma unroll
    for (int ni = 0; ni < 4; ++ni) acc[mi][ni] = (f32x4){0.f, 0.f, 0.f, 0.f};

#pragma unroll
  for (int mi = 0; mi < 4; ++mi) {
    bf16x8 a[4];
#pragma unroll
    for (int st = 0; st < 4; ++st)
      a[st] = *(const bf16x8*)(sA + ((wr * 4 + mi) * 4 + st) * 512 + lane * 8);
#pragma unroll
    for (int ni = 0; ni < 4; ++ni) {
#pragma unroll
      for (int st = 0; st < 4; ++st) {
        bf16x8 b = *(const bf16x8*)(sB + ((wc * 4 + ni) * 4 + st) * 512 + lane * 8);
        if (MODE <= 1)
          acc[mi][ni] = __builtin_amdgcn_mfma_f32_16x16x32_bf16(b, a[st], acc[mi][ni], 0, 0, 0);
        else
          acc[mi][ni] = __builtin_amdgcn_mfma_f32_16x16x32_bf16(a[st], b, acc[mi][ni], 0, 0, 0);
      }
    }
  }

  if (MODE == 0) {
    // C rows = n (l4*4+r), cols = s (l15). h = ntile. Row-major [b,h,s,d].
#pragma unroll
    for (int mi = 0; mi < 4; ++mi) {
      int sg = m0 + wr * 64 + mi * 16 + l15;
      int bb = sg >> 11, s = sg & 2047;
      short* orow = out + ((size_t)(bb * H_ + ntile) * S_ + s) * D_;
#pragma unroll
      for (int ni = 0; ni < 4; ++ni) {
        int d0 = wc * 64 + ni * 16 + l4 * 4;
        float4 bv = *(const float4*)(bias + n0 + d0);
        f32x4 t = acc[mi][ni];
        t[0] += bv.x; t[1] += bv.y; t[2] += bv.z; t[3] += bv.w;
        *(short4*)(orow + d0) = pack4(t);
      }
    }
  } else if (MODE == 1) {
    // C rows = n/d (l4*4+r), cols = s/key (l15). K fragment-linear store.
#pragma unroll
    for (int mi = 0; mi < 4; ++mi) {
      int key = m0 + wr * 64 + mi * 16 + l15;
      int bb = key >> 11, k = key & 2047;
      size_t base = (size_t)(bb * H_ + ntile) * (S_ * D_) + (size_t)(k >> 6) * 8192
                  + ((k >> 4) & 3) * 4 * 512 + (k & 15) * 8;
#pragma unroll
      for (int ni = 0; ni < 4; ++ni) {
        int d0 = wc * 64 + ni * 16 + l4 * 4;
        float4 bv = *(const float4*)(bias + n0 + d0);
        f32x4 t = acc[mi][ni];
        t[0] += bv.x; t[1] += bv.y; t[2] += bv.z; t[3] += bv.w;
        size_t off = base + (size_t)(d0 >> 5) * 512 + ((d0 >> 3) & 3) * 128 + (d0 & 7);
        *(short4*)(out + off) = pack4(t);
      }
    }
  } else {
    // C rows = s/key (l4*4+r), cols = n/d (l15). V fragment-linear store.
#pragma unroll
    for (int ni = 0; ni < 4; ++ni) {
      int d = wc * 64 + ni * 16 + l15;
      float bvs = bias[n0 + d];
#pragma unroll
      for (int mi = 0; mi < 4; ++mi) {
        int sg0 = m0 + wr * 64 + mi * 16 + l4 * 4;
        int bb = sg0 >> 11, s0 = sg0 & 2047;
        f32x4 t = acc[mi][ni];
        t[0] += bvs; t[1] += bvs; t[2] += bvs; t[3] += bvs;
        size_t off = (size_t)(bb * H_ + ntile) * (S_ * D_)
                   + (size_t)(s0 >> 6) * 8192
                   + (size_t)((d >> 4) * 2 + ((s0 >> 5) & 1)) * 512
                   + ((s0 >> 3) & 3) * 128 + (d & 15) * 8
                   + (s0 & 7);
        *(short4*)(out + off) = pack4(t);
      }
    }
  }
}

// 1536 blocks = 3 projs x 64 m-tiles x 8 n-tiles, n fastest, XCD chunk-swizzled.
__global__ __launch_bounds__(256, 3) void proj3(
    const float* __restrict__ xq, const float* __restrict__ xk, const float* __restrict__ xv,
    const short* __restrict__ wtq, const short* __restrict__ wtk, const short* __restrict__ wtv,
    const float* __restrict__ bQ, const float* __restrict__ bK, const float* __restrict__ bV,
    short* __restrict__ Qp, short* __restrict__ Kf, short* __restrict__ Vf) {
  __shared__ short sA[16384], sB[16384];
  int work = (blockIdx.x & 7) * 192 + (blockIdx.x >> 3);
  int which = work >> 9;
  int t = work & 511;
  int mtile = t >> 3, ntile = t & 7;
  if (which == 0)      proj_tile<0>(xq, wtq, bQ, Qp, mtile, ntile, sA, sB);
  else if (which == 1) proj_tile<1>(xk, wtk, bK, Kf, mtile, ntile, sA, sB);
  else                 proj_tile<2>(xv, wtv, bV, Vf, mtile, ntile, sA, sB);
}

// Flash-style attention with |score| softmax, NO max tracking.
// BARRIER-FREE + REGISTER-PIPELINED HALF-TILES (32 keys per step):
//  - K is register double-buffered ONE half-step ahead (kfA/kfB ping-pong):
//    QK(h) reads registers whose loads issued a full step earlier (~900 cy
//    cover) -> the vmcnt wait that bounded r1/r4/r5/r7 is satisfied-on-arrival.
//  - V(h) issued at step start, consumed at PV after QK+SM (~500 cy cover).
//  - No shared LDS, no __syncthreads(); sP is per-wave private (DS in-order).
// Accumulation order per score / ls / o[t8] identical to prior rounds ->
// bit-identical output (absmax 0.0004882812).
#define PSTR 72  // P row stride (shorts)

#define HSTEP(KC, KN, H, DOISS)                                                \
  {                                                                            \
    if (DOISS) {                                                               \
      _Pragma("unroll") for (int j = 0; j < 8; ++j)                            \
        KN[j] = *(const bf16x8*)(kfb + ((H) + 1) * 4096 + j * 512);            \
    }                                                                          \
    bf16x8 bv[8];                                                              \
    _Pragma("unroll") for (int j = 0; j < 8; ++j)                              \
      bv[j] = *(const bf16x8*)(vfb + ((H) >> 1) * 8192 + (j * 2 + ((H) & 1)) * 512); \
    __builtin_amdgcn_sched_barrier(0);                                         \
    f32x4 s0[2], s1[2];                                                        \
    __builtin_amdgcn_s_setprio(1);                                             \
    _Pragma("unroll") for (int m = 0; m < 2; ++m) {                            \
      s0[m] = (f32x4){0.f, 0.f, 0.f, 0.f};                                     \
      s1[m] = (f32x4){0.f, 0.f, 0.f, 0.f};                                     \
      _Pragma("unroll") for (int st = 0; st < 4; ++st) {                       \
        s0[m] = __builtin_amdgcn_mfma_f32_16x16x32_bf16(KC[m * 4 + st], aq[0][st], s0[m], 0, 0, 0); \
        s1[m] = __builtin_amdgcn_mfma_f32_16x16x32_bf16(KC[m * 4 + st], aq[1][st], s1[m], 0, 0, 0); \
      }                                                                        \
    }                                                                          \
    __builtin_amdgcn_s_setprio(0);                                             \
    bf16x8 ap0, ap1;                                                           \
    _Pragma("unroll") for (int m = 0; m < 2; ++m) {                            \
      _Pragma("unroll") for (int r = 0; r < 4; ++r) {                          \
        float p = __builtin_amdgcn_exp2f(fabsf(s0[m][r]) * SC2);               \
        ls0 += p;                                                              \
        s0[m][r] = p;                                                          \
      }                                                                        \
      *(short4*)(pw + l15 * PSTR + m * 16 + l4 * 4) = pack4(s0[m]);            \
    }                                                                          \
    ap0 = *(const bf16x8*)(pw + l15 * PSTR + l4 * 8);                          \
    _Pragma("unroll") for (int m = 0; m < 2; ++m) {                            \
      _Pragma("unroll") for (int r = 0; r < 4; ++r) {                          \
        float p = __builtin_amdgcn_exp2f(fabsf(s1[m][r]) * SC2);               \
        ls1 += p;                                                              \
        s1[m][r] = p;                                                          \
      }                                                                        \
      *(short4*)(pw + l15 * PSTR + m * 16 + l4 * 4) = pack4(s1[m]);            \
    }                                                                          \
    ap1 = *(const bf16x8*)(pw + l15 * PSTR + l4 * 8);                          \
    __builtin_amdgcn_s_setprio(1);                                             \
    _Pragma("unroll") for (int t8 = 0; t8 < 8; ++t8) {                         \
      o0[t8] = __builtin_amdgcn_mfma_f32_16x16x32_bf16(ap0, bv[t8], o0[t8], 0, 0, 0); \
      o1[t8] = __builtin_amdgcn_mfma_f32_16x16x32_bf16(ap1, bv[t8], o1[t8], 0, 0, 0); \
    }                                                                          \
    __builtin_amdgcn_s_setprio(0);                                             \
  }

__global__ __launch_bounds__(256, 2) void attn(const short* __restrict__ Qp,
                                               const short* __restrict__ Kf,
                                               const short* __restrict__ Vf,
                                               float* __restrict__ out) {
  __shared__ short sP[4 * 16 * PSTR];  // per-wave P region (only LDS in kernel)

  int tid = threadIdx.x;
  int lane = tid & 63, w = tid >> 6;
  // Swizzle: bijective XCD chunking + INTERLEAVED bh within the chunk, so the
  // two blocks a CU hosts (round-robin: idx and idx+32) share bh -> identical
  // K/V streams -> L1 (32 KB) serves the second block's reads.
  int xcd = blockIdx.x & 7;
  int idx = blockIdx.x >> 3;           // 0..63 within XCD chunk
  int bh  = xcd * 4 + (idx & 3);       // 0..31
  int qt  = idx >> 2;                  // 0..15
  int q0 = qt * 128;
  int l15 = lane & 15, l4 = lane >> 4;

  const short* Qbase = Qp + (size_t)bh * S_ * D_;
  const short* kfb = Kf + (size_t)bh * S_ * D_ + lane * 8;  // frag-linear K
  const short* vfb = Vf + (size_t)bh * S_ * D_ + lane * 8;  // frag-linear V

  // Q B-fragments for two 16-q groups (q = q0 + w*32 + g*16 + l15)
  bf16x8 aq[2][4];
#pragma unroll
  for (int g = 0; g < 2; ++g)
#pragma unroll
    for (int st = 0; st < 4; ++st)
      aq[g][st] = *(const bf16x8*)(Qbase + (q0 + w * 32 + g * 16 + l15) * D_ + l4 * 8 + 32 * st);

  f32x4 o0[8], o1[8];
#pragma unroll
  for (int t = 0; t < 8; ++t) {
    o0[t] = (f32x4){0.f, 0.f, 0.f, 0.f};
    o1[t] = (f32x4){0.f, 0.f, 0.f, 0.f};
  }
  float ls0 = 0.f, ls1 = 0.f;

  const float SC2 = 0.127530637f; // log2(e)/sqrt(128)
  short* pw = sP + w * 16 * PSTR;

  // prologue: load K half 0 into kfA
  bf16x8 kfA[8], kfB[8];
#pragma unroll
  for (int j = 0; j < 8; ++j)
    kfA[j] = *(const bf16x8*)(kfb + j * 512);

  for (int t = 0; t < 32; ++t) {
    HSTEP(kfA, kfB, 2 * t, true);
    HSTEP(kfB, kfA, 2 * t + 1, (t < 31));
  }

  // final softmax denominators: per-lane partial sums -> quad reduce
  ls0 += __shfl_xor(ls0, 16);
  ls0 += __shfl_xor(ls0, 32);
  ls1 += __shfl_xor(ls1, 16);
  ls1 += __shfl_xor(ls1, 32);
  float inv0[4], inv1[4];
#pragma unroll
  for (int r = 0; r < 4; ++r) {
    inv0[r] = 1.f / __shfl(ls0, l4 * 4 + r);
    inv1[r] = 1.f / __shfl(ls1, l4 * 4 + r);
  }

  // epilogue: out[b, q, h*128 + dv] fp32
  int bb = bh >> 3, h = bh & 7;
#pragma unroll
  for (int t = 0; t < 8; ++t) {
#pragma unroll
    for (int r = 0; r < 4; ++r) {
      int qA = q0 + w * 32 + l4 * 4 + r;
      int qB = qA + 16;
      out[((size_t)(bb * S_ + qA)) * (H_ * D_) + h * D_ + t * 16 + l15] = o0[t][r] * inv0[r];
      out[((size_t)(bb * S_ + qB)) * (H_ * D_) + h * D_ + t * 16 + l15] = o1[t][r] * inv1[r];
    }
  }
}

extern "C" void kernel_launch(void* const* d_in, const int* in_sizes, int n_in,
                              void* d_out, int out_size, void* d_ws, size_t ws_size,
                              hipStream_t stream) {
  (void)in_sizes; (void)n_in; (void)out_size; (void)ws_size;
  const float* q  = (const float*)d_in[0];
  const float* k  = (const float*)d_in[1];
  const float* v  = (const float*)d_in[2];
  const float* WQ = (const float*)d_in[3];
  const float* bQ = (const float*)d_in[4];
  const float* WK = (const float*)d_in[5];
  const float* bK = (const float*)d_in[6];
  const float* WV = (const float*)d_in[7];
  const float* bV = (const float*)d_in[8];

  const int NW = D_ * H_ * D_;      // 131072 per weight
  const int NP = B_ * H_ * S_ * D_; // 8388608 per projected tensor

  short* ws  = (short*)d_ws;
  short* wtq = ws;
  short* wtk = wtq + NW;
  short* wtv = wtk + NW;
  short* Qp  = wtv + NW;
  short* Kf  = Qp + NP;
  short* Vf  = Kf + NP;

  prep<<<96, 256, 0, stream>>>(WQ, WK, WV, wtq, wtk, wtv);

  proj3<<<1536, 256, 0, stream>>>(q, k, v, wtq, wtk, wtv, bQ, bK, bV, Qp, Kf, Vf);

  attn<<<512, 256, 0, stream>>>(Qp, Kf, Vf, (float*)d_out);
}

// Round 9
// 184.443 us; speedup vs baseline: 1.2672x; 1.0094x over previous
//
#include <hip/hip_runtime.h>
#include <hip/hip_bf16.h>

// Problem constants
#define B_ 4
#define S_ 2048
#define D_ 128
#define H_ 8

typedef __attribute__((ext_vector_type(8))) short bf16x8;
typedef __attribute__((ext_vector_type(4))) float f32x4;

__device__ __forceinline__ short f2bf(float f) {
  union { float f; unsigned u; } v; v.f = f;
  unsigned u = v.u;
  unsigned r = (u + 0x7FFFu + ((u >> 16) & 1u)) >> 16;
  return (short)r;
}

// pack 4 fp32 -> 4 bf16 (RNE) as short4
__device__ __forceinline__ short4 pack4(f32x4 p) {
  union { __hip_bfloat162 h2[2]; short4 s4; } u;
  u.h2[0] = __float22bfloat162_rn(make_float2(p[0], p[1]));
  u.h2[1] = __float22bfloat162_rn(make_float2(p[2], p[3]));
  return u.s4;
}

// prep: transpose+convert W (128,1024) fp32 -> FRAGMENT-LINEAR bf16 image:
//   WF[ntile][f][lane][e], f = ((n>>4)&7)*4 + (k>>5), lane = ((k>>3)&3)*16 + (n&15),
//   e = k&7.  proj reads its 16 B-frags as contiguous 1 KB wave-loads from L2.
__global__ __launch_bounds__(256) void prep(
    const float* __restrict__ WQ, const float* __restrict__ WK, const float* __restrict__ WV,
    short* __restrict__ FQ, short* __restrict__ FK, short* __restrict__ FV) {
  __shared__ float tile[64][65];
  int bw = blockIdx.x >> 5;
  int tl = blockIdx.x & 31;
  int n0 = (tl & 15) * 64, k0 = (tl >> 4) * 64;
  const float* W = (bw == 0) ? WQ : (bw == 1) ? WK : WV;
  short* WF = (bw == 0) ? FQ : (bw == 1) ? FK : FV;
#pragma unroll
  for (int i = 0; i < 16; ++i) {
    int cix = threadIdx.x + 256 * i;
    int rr = cix >> 6, cc = cix & 63;
    tile[rr][cc] = W[(k0 + rr) * 1024 + n0 + cc];
  }
  __syncthreads();
#pragma unroll
  for (int i = 0; i < 16; ++i) {
    int cix = threadIdx.x + 256 * i;
    int rr = cix >> 6, cc = cix & 63;   // rr = n-local, cc = k-local
    int n = n0 + rr, k = k0 + cc;
    size_t off = (size_t)(n >> 7) * 16384
               + (size_t)(((n >> 4) & 7) * 4 + (k >> 5)) * 512
               + ((k >> 3) & 3) * 128 + (n & 15) * 8 + (k & 7);
    WF[off] = f2bf(tile[cc][rr]);
  }
}

// ---------------------------------------------------------------------------
// Tiled projection: block = 128(M:s) x 128(N:h*128+d) output tile, K=128.
// A-staging: fp32 load -> RNE cvt -> ds_write into fragment-order LDS (32 KB).
// B: 16 fragment-linear 1 KB wave-loads from L2 into registers (no LDS, no DMA)
//    -> LDS halves vs r8, occupancy 2 -> 3 blocks/CU; LDS reads/wave 80 -> 16.
// MODE 0 (Q): out[b,h,s,d] row-major, short4 stores.
// MODE 1 (K): fragment-linear image KF (see r8 comment).
// MODE 2 (V): fragment-linear image VF (see r8 comment).
// Same f2bf values, same MFMA order -> bit-identical outputs.
// ---------------------------------------------------------------------------
template <int MODE>
__device__ __forceinline__ void proj_tile(const float* __restrict__ X,
                                          const short* __restrict__ WF,
                                          const float* __restrict__ bias,
                                          short* __restrict__ out,
                                          int mtile, int ntile,
                                          short* sA) {
  int tid = threadIdx.x;
  int lane = tid & 63, w = tid >> 6;
  int l15 = lane & 15, l4 = lane >> 4;
  int m0 = mtile * 128, n0 = ntile * 128;

  // A frags: fp32 load -> cvt -> ds_write (fragment-order image)
#pragma unroll
  for (int j = 0; j < 8; ++j) {
    int f = w * 8 + j;
    const float* src = X + (size_t)(m0 + (f >> 2) * 16 + l15) * 128 + (f & 3) * 32 + l4 * 8;
    float4 v0 = *(const float4*)src;
    float4 v1 = *(const float4*)(src + 4);
    union { struct { short4 lo, hi; } s; bf16x8 v; } u;
    u.s.lo = pack4((f32x4){v0.x, v0.y, v0.z, v0.w});
    u.s.hi = pack4((f32x4){v1.x, v1.y, v1.z, v1.w});
    *(bf16x8*)(sA + f * 512 + lane * 8) = u.v;
  }

  int wr = w >> 1, wc = w & 1;  // wave -> 64x64 quadrant

  // B frags for this wave's wc-half: 16 contiguous 1 KB wave-loads from L2.
  const short* wfb = WF + (size_t)ntile * 16384 + wc * 8192 + lane * 8;
  bf16x8 b[16];
#pragma unroll
  for (int q = 0; q < 16; ++q)
    b[q] = *(const bf16x8*)(wfb + q * 512);

  __syncthreads();  // A image complete

  f32x4 acc[4][4];
#pragma unroll
  for (int mi = 0; mi < 4; ++mi)
#pragma unroll
    for (int ni = 0; ni < 4; ++ni) acc[mi][ni] = (f32x4){0.f, 0.f, 0.f, 0.f};

#pragma unroll
  for (int mi = 0; mi < 4; ++mi) {
    bf16x8 a[4];
#pragma unroll
    for (int st = 0; st < 4; ++st)
      a[st] = *(const bf16x8*)(sA + ((wr * 4 + mi) * 4 + st) * 512 + lane * 8);
#pragma unroll
    for (int ni = 0; ni < 4; ++ni) {
#pragma unroll
      for (int st = 0; st < 4; ++st) {
        if (MODE <= 1)
          acc[mi][ni] = __builtin_amdgcn_mfma_f32_16x16x32_bf16(b[ni * 4 + st], a[st], acc[mi][ni], 0, 0, 0);
        else
          acc[mi][ni] = __builtin_amdgcn_mfma_f32_16x16x32_bf16(a[st], b[ni * 4 + st], acc[mi][ni], 0, 0, 0);
      }
    }
  }

  if (MODE == 0) {
    // C rows = n (l4*4+r), cols = s (l15). h = ntile. Row-major [b,h,s,d].
#pragma unroll
    for (int mi = 0; mi < 4; ++mi) {
      int sg = m0 + wr * 64 + mi * 16 + l15;
      int bb = sg >> 11, s = sg & 2047;
      short* orow = out + ((size_t)(bb * H_ + ntile) * S_ + s) * D_;
#pragma unroll
      for (int ni = 0; ni < 4; ++ni) {
        int d0 = wc * 64 + ni * 16 + l4 * 4;
        float4 bv = *(const float4*)(bias + n0 + d0);
        f32x4 t = acc[mi][ni];
        t[0] += bv.x; t[1] += bv.y; t[2] += bv.z; t[3] += bv.w;
        *(short4*)(orow + d0) = pack4(t);
      }
    }
  } else if (MODE == 1) {
    // K fragment-linear store.
#pragma unroll
    for (int mi = 0; mi < 4; ++mi) {
      int key = m0 + wr * 64 + mi * 16 + l15;
      int bb = key >> 11, k = key & 2047;
      size_t base = (size_t)(bb * H_ + ntile) * (S_ * D_) + (size_t)(k >> 6) * 8192
                  + ((k >> 4) & 3) * 4 * 512 + (k & 15) * 8;
#pragma unroll
      for (int ni = 0; ni < 4; ++ni) {
        int d0 = wc * 64 + ni * 16 + l4 * 4;
        float4 bv = *(const float4*)(bias + n0 + d0);
        f32x4 t = acc[mi][ni];
        t[0] += bv.x; t[1] += bv.y; t[2] += bv.z; t[3] += bv.w;
        size_t off = base + (size_t)(d0 >> 5) * 512 + ((d0 >> 3) & 3) * 128 + (d0 & 7);
        *(short4*)(out + off) = pack4(t);
      }
    }
  } else {
    // V fragment-linear store.
#pragma unroll
    for (int ni = 0; ni < 4; ++ni) {
      int d = wc * 64 + ni * 16 + l15;
      float bvs = bias[n0 + d];
#pragma unroll
      for (int mi = 0; mi < 4; ++mi) {
        int sg0 = m0 + wr * 64 + mi * 16 + l4 * 4;
        int bb = sg0 >> 11, s0 = sg0 & 2047;
        f32x4 t = acc[mi][ni];
        t[0] += bvs; t[1] += bvs; t[2] += bvs; t[3] += bvs;
        size_t off = (size_t)(bb * H_ + ntile) * (S_ * D_)
                   + (size_t)(s0 >> 6) * 8192
                   + (size_t)((d >> 4) * 2 + ((s0 >> 5) & 1)) * 512
                   + ((s0 >> 3) & 3) * 128 + (d & 15) * 8
                   + (s0 & 7);
        *(short4*)(out + off) = pack4(t);
      }
    }
  }
}

// 1536 blocks = 3 projs x 64 m-tiles x 8 n-tiles, n fastest, XCD chunk-swizzled.
// LDS 32 KB/block -> 3 blocks/CU (96 KB); VGPR cap 170 at 3 waves/EU.
__global__ __launch_bounds__(256, 3) void proj3(
    const float* __restrict__ xq, const float* __restrict__ xk, const float* __restrict__ xv,
    const short* __restrict__ wtq, const short* __restrict__ wtk, const short* __restrict__ wtv,
    const float* __restrict__ bQ, const float* __restrict__ bK, const float* __restrict__ bV,
    short* __restrict__ Qp, short* __restrict__ Kf, short* __restrict__ Vf) {
  __shared__ short sA[16384];
  int work = (blockIdx.x & 7) * 192 + (blockIdx.x >> 3);
  int which = work >> 9;
  int t = work & 511;
  int mtile = t >> 3, ntile = t & 7;
  if (which == 0)      proj_tile<0>(xq, wtq, bQ, Qp, mtile, ntile, sA);
  else if (which == 1) proj_tile<1>(xk, wtk, bK, Kf, mtile, ntile, sA);
  else                 proj_tile<2>(xv, wtv, bV, Vf, mtile, ntile, sA);
}

// Flash-style attention with |score| softmax, NO max tracking.
// BARRIER-FREE + REGISTER-PIPELINED HALF-TILES (32 keys per step) — r8 kernel,
// byte-identical (its counters double as the noise control this round).
#define PSTR 72  // P row stride (shorts)

#define HSTEP(KC, KN, H, DOISS)                                                \
  {                                                                            \
    if (DOISS) {                                                               \
      _Pragma("unroll") for (int j = 0; j < 8; ++j)                            \
        KN[j] = *(const bf16x8*)(kfb + ((H) + 1) * 4096 + j * 512);            \
    }                                                                          \
    bf16x8 bv[8];                                                              \
    _Pragma("unroll") for (int j = 0; j < 8; ++j)                              \
      bv[j] = *(const bf16x8*)(vfb + ((H) >> 1) * 8192 + (j * 2 + ((H) & 1)) * 512); \
    __builtin_amdgcn_sched_barrier(0);                                         \
    f32x4 s0[2], s1[2];                                                        \
    __builtin_amdgcn_s_setprio(1);                                             \
    _Pragma("unroll") for (int m = 0; m < 2; ++m) {                            \
      s0[m] = (f32x4){0.f, 0.f, 0.f, 0.f};                                     \
      s1[m] = (f32x4){0.f, 0.f, 0.f, 0.f};                                     \
      _Pragma("unroll") for (int st = 0; st < 4; ++st) {                       \
        s0[m] = __builtin_amdgcn_mfma_f32_16x16x32_bf16(KC[m * 4 + st], aq[0][st], s0[m], 0, 0, 0); \
        s1[m] = __builtin_amdgcn_mfma_f32_16x16x32_bf16(KC[m * 4 + st], aq[1][st], s1[m], 0, 0, 0); \
      }                                                                        \
    }                                                                          \
    __builtin_amdgcn_s_setprio(0);                                             \
    bf16x8 ap0, ap1;                                                           \
    _Pragma("unroll") for (int m = 0; m < 2; ++m) {                            \
      _Pragma("unroll") for (int r = 0; r < 4; ++r) {                          \
        float p = __builtin_amdgcn_exp2f(fabsf(s0[m][r]) * SC2);               \
        ls0 += p;                                                              \
        s0[m][r] = p;                                                          \
      }                                                                        \
      *(short4*)(pw + l15 * PSTR + m * 16 + l4 * 4) = pack4(s0[m]);            \
    }                                                                          \
    ap0 = *(const bf16x8*)(pw + l15 * PSTR + l4 * 8);                          \
    _Pragma("unroll") for (int m = 0; m < 2; ++m) {                            \
      _Pragma("unroll") for (int r = 0; r < 4; ++r) {                          \
        float p = __builtin_amdgcn_exp2f(fabsf(s1[m][r]) * SC2);               \
        ls1 += p;                                                              \
        s1[m][r] = p;                                                          \
      }                                                                        \
      *(short4*)(pw + l15 * PSTR + m * 16 + l4 * 4) = pack4(s1[m]);            \
    }                                                                          \
    ap1 = *(const bf16x8*)(pw + l15 * PSTR + l4 * 8);                          \
    __builtin_amdgcn_s_setprio(1);                                             \
    _Pragma("unroll") for (int t8 = 0; t8 < 8; ++t8) {                         \
      o0[t8] = __builtin_amdgcn_mfma_f32_16x16x32_bf16(ap0, bv[t8], o0[t8], 0, 0, 0); \
      o1[t8] = __builtin_amdgcn_mfma_f32_16x16x32_bf16(ap1, bv[t8], o1[t8], 0, 0, 0); \
    }                                                                          \
    __builtin_amdgcn_s_setprio(0);                                             \
  }

__global__ __launch_bounds__(256, 2) void attn(const short* __restrict__ Qp,
                                               const short* __restrict__ Kf,
                                               const short* __restrict__ Vf,
                                               float* __restrict__ out) {
  __shared__ short sP[4 * 16 * PSTR];  // per-wave P region (only LDS in kernel)

  int tid = threadIdx.x;
  int lane = tid & 63, w = tid >> 6;
  int xcd = blockIdx.x & 7;
  int idx = blockIdx.x >> 3;           // 0..63 within XCD chunk
  int bh  = xcd * 4 + (idx & 3);       // 0..31
  int qt  = idx >> 2;                  // 0..15
  int q0 = qt * 128;
  int l15 = lane & 15, l4 = lane >> 4;

  const short* Qbase = Qp + (size_t)bh * S_ * D_;
  const short* kfb = Kf + (size_t)bh * S_ * D_ + lane * 8;  // frag-linear K
  const short* vfb = Vf + (size_t)bh * S_ * D_ + lane * 8;  // frag-linear V

  // Q B-fragments for two 16-q groups (q = q0 + w*32 + g*16 + l15)
  bf16x8 aq[2][4];
#pragma unroll
  for (int g = 0; g < 2; ++g)
#pragma unroll
    for (int st = 0; st < 4; ++st)
      aq[g][st] = *(const bf16x8*)(Qbase + (q0 + w * 32 + g * 16 + l15) * D_ + l4 * 8 + 32 * st);

  f32x4 o0[8], o1[8];
#pragma unroll
  for (int t = 0; t < 8; ++t) {
    o0[t] = (f32x4){0.f, 0.f, 0.f, 0.f};
    o1[t] = (f32x4){0.f, 0.f, 0.f, 0.f};
  }
  float ls0 = 0.f, ls1 = 0.f;

  const float SC2 = 0.127530637f; // log2(e)/sqrt(128)
  short* pw = sP + w * 16 * PSTR;

  // prologue: load K half 0 into kfA
  bf16x8 kfA[8], kfB[8];
#pragma unroll
  for (int j = 0; j < 8; ++j)
    kfA[j] = *(const bf16x8*)(kfb + j * 512);

  for (int t = 0; t < 32; ++t) {
    HSTEP(kfA, kfB, 2 * t, true);
    HSTEP(kfB, kfA, 2 * t + 1, (t < 31));
  }

  // final softmax denominators: per-lane partial sums -> quad reduce
  ls0 += __shfl_xor(ls0, 16);
  ls0 += __shfl_xor(ls0, 32);
  ls1 += __shfl_xor(ls1, 16);
  ls1 += __shfl_xor(ls1, 32);
  float inv0[4], inv1[4];
#pragma unroll
  for (int r = 0; r < 4; ++r) {
    inv0[r] = 1.f / __shfl(ls0, l4 * 4 + r);
    inv1[r] = 1.f / __shfl(ls1, l4 * 4 + r);
  }

  // epilogue: out[b, q, h*128 + dv] fp32
  int bb = bh >> 3, h = bh & 7;
#pragma unroll
  for (int t = 0; t < 8; ++t) {
#pragma unroll
    for (int r = 0; r < 4; ++r) {
      int qA = q0 + w * 32 + l4 * 4 + r;
      int qB = qA + 16;
      out[((size_t)(bb * S_ + qA)) * (H_ * D_) + h * D_ + t * 16 + l15] = o0[t][r] * inv0[r];
      out[((size_t)(bb * S_ + qB)) * (H_ * D_) + h * D_ + t * 16 + l15] = o1[t][r] * inv1[r];
    }
  }
}

extern "C" void kernel_launch(void* const* d_in, const int* in_sizes, int n_in,
                              void* d_out, int out_size, void* d_ws, size_t ws_size,
                              hipStream_t stream) {
  (void)in_sizes; (void)n_in; (void)out_size; (void)ws_size;
  const float* q  = (const float*)d_in[0];
  const float* k  = (const float*)d_in[1];
  const float* v  = (const float*)d_in[2];
  const float* WQ = (const float*)d_in[3];
  const float* bQ = (const float*)d_in[4];
  const float* WK = (const float*)d_in[5];
  const float* bK = (const float*)d_in[6];
  const float* WV = (const float*)d_in[7];
  const float* bV = (const float*)d_in[8];

  const int NW = D_ * H_ * D_;      // 131072 per weight
  const int NP = B_ * H_ * S_ * D_; // 8388608 per projected tensor

  short* ws  = (short*)d_ws;
  short* wtq = ws;
  short* wtk = wtq + NW;
  short* wtv = wtk + NW;
  short* Qp  = wtv + NW;
  short* Kf  = Qp + NP;
  short* Vf  = Kf + NP;

  prep<<<96, 256, 0, stream>>>(WQ, WK, WV, wtq, wtk, wtv);

  proj3<<<1536, 256, 0, stream>>>(q, k, v, wtq, wtk, wtv, bQ, bK, bV, Qp, Kf, Vf);

  attn<<<512, 256, 0, stream>>>(Qp, Kf, Vf, (float*)d_out);
}

// Round 10
// 183.966 us; speedup vs baseline: 1.2705x; 1.0026x over previous
//
#include <hip/hip_runtime.h>
#include <hip/hip_bf16.h>

// Problem constants
#define B_ 4
#define S_ 2048
#define D_ 128
#define H_ 8

typedef __attribute__((ext_vector_type(8))) short bf16x8;
typedef __attribute__((ext_vector_type(4))) float f32x4;

__device__ __forceinline__ short f2bf(float f) {
  union { float f; unsigned u; } v; v.f = f;
  unsigned u = v.u;
  unsigned r = (u + 0x7FFFu + ((u >> 16) & 1u)) >> 16;
  return (short)r;
}

// pack 4 fp32 -> 4 bf16 (RNE) as short4
__device__ __forceinline__ short4 pack4(f32x4 p) {
  union { __hip_bfloat162 h2[2]; short4 s4; } u;
  u.h2[0] = __float22bfloat162_rn(make_float2(p[0], p[1]));
  u.h2[1] = __float22bfloat162_rn(make_float2(p[2], p[3]));
  return u.s4;
}

// async global->LDS DMA, 16 B per lane. LDS dest = wave-uniform base + lane*16.
__device__ __forceinline__ void dma16(const short* g, short* l) {
  __builtin_amdgcn_global_load_lds(
      (const __attribute__((address_space(1))) unsigned int*)g,
      (__attribute__((address_space(3))) unsigned int*)l, 16, 0, 0);
}

// prep: transpose+convert W (128,1024) fp32 -> FRAGMENT-LINEAR bf16 image:
//   WF[ntile][f][lane][e], f = ((n>>4)&7)*4 + (k>>5), lane = ((k>>3)&3)*16 + (n&15),
//   e = k&7.  proj reads its 16 B-frags as contiguous 1 KB wave-loads from L2.
__global__ __launch_bounds__(256) void prep(
    const float* __restrict__ WQ, const float* __restrict__ WK, const float* __restrict__ WV,
    short* __restrict__ FQ, short* __restrict__ FK, short* __restrict__ FV) {
  __shared__ float tile[64][65];
  int bw = blockIdx.x >> 5;
  int tl = blockIdx.x & 31;
  int n0 = (tl & 15) * 64, k0 = (tl >> 4) * 64;
  const float* W = (bw == 0) ? WQ : (bw == 1) ? WK : WV;
  short* WF = (bw == 0) ? FQ : (bw == 1) ? FK : FV;
#pragma unroll
  for (int i = 0; i < 16; ++i) {
    int cix = threadIdx.x + 256 * i;
    int rr = cix >> 6, cc = cix & 63;
    tile[rr][cc] = W[(k0 + rr) * 1024 + n0 + cc];
  }
  __syncthreads();
#pragma unroll
  for (int i = 0; i < 16; ++i) {
    int cix = threadIdx.x + 256 * i;
    int rr = cix >> 6, cc = cix & 63;   // rr = n-local, cc = k-local
    int n = n0 + rr, k = k0 + cc;
    size_t off = (size_t)(n >> 7) * 16384
               + (size_t)(((n >> 4) & 7) * 4 + (k >> 5)) * 512
               + ((k >> 3) & 3) * 128 + (n & 15) * 8 + (k & 7);
    WF[off] = f2bf(tile[cc][rr]);
  }
}

// ---------------------------------------------------------------------------
// Tiled projection (r9 kernel, unchanged): block = 128x128 output tile, K=128.
// ---------------------------------------------------------------------------
template <int MODE>
__device__ __forceinline__ void proj_tile(const float* __restrict__ X,
                                          const short* __restrict__ WF,
                                          const float* __restrict__ bias,
                                          short* __restrict__ out,
                                          int mtile, int ntile,
                                          short* sA) {
  int tid = threadIdx.x;
  int lane = tid & 63, w = tid >> 6;
  int l15 = lane & 15, l4 = lane >> 4;
  int m0 = mtile * 128, n0 = ntile * 128;

  // A frags: fp32 load -> cvt -> ds_write (fragment-order image)
#pragma unroll
  for (int j = 0; j < 8; ++j) {
    int f = w * 8 + j;
    const float* src = X + (size_t)(m0 + (f >> 2) * 16 + l15) * 128 + (f & 3) * 32 + l4 * 8;
    float4 v0 = *(const float4*)src;
    float4 v1 = *(const float4*)(src + 4);
    union { struct { short4 lo, hi; } s; bf16x8 v; } u;
    u.s.lo = pack4((f32x4){v0.x, v0.y, v0.z, v0.w});
    u.s.hi = pack4((f32x4){v1.x, v1.y, v1.z, v1.w});
    *(bf16x8*)(sA + f * 512 + lane * 8) = u.v;
  }

  int wr = w >> 1, wc = w & 1;  // wave -> 64x64 quadrant

  // B frags for this wave's wc-half: 16 contiguous 1 KB wave-loads from L2.
  const short* wfb = WF + (size_t)ntile * 16384 + wc * 8192 + lane * 8;
  bf16x8 b[16];
#pragma unroll
  for (int q = 0; q < 16; ++q)
    b[q] = *(const bf16x8*)(wfb + q * 512);

  __syncthreads();  // A image complete

  f32x4 acc[4][4];
#pragma unroll
  for (int mi = 0; mi < 4; ++mi)
#pragma unroll
    for (int ni = 0; ni < 4; ++ni) acc[mi][ni] = (f32x4){0.f, 0.f, 0.f, 0.f};

#pragma unroll
  for (int mi = 0; mi < 4; ++mi) {
    bf16x8 a[4];
#pragma unroll
    for (int st = 0; st < 4; ++st)
      a[st] = *(const bf16x8*)(sA + ((wr * 4 + mi) * 4 + st) * 512 + lane * 8);
#pragma unroll
    for (int ni = 0; ni < 4; ++ni) {
#pragma unroll
      for (int st = 0; st < 4; ++st) {
        if (MODE <= 1)
          acc[mi][ni] = __builtin_amdgcn_mfma_f32_16x16x32_bf16(b[ni * 4 + st], a[st], acc[mi][ni], 0, 0, 0);
        else
          acc[mi][ni] = __builtin_amdgcn_mfma_f32_16x16x32_bf16(a[st], b[ni * 4 + st], acc[mi][ni], 0, 0, 0);
      }
    }
  }

  if (MODE == 0) {
#pragma unroll
    for (int mi = 0; mi < 4; ++mi) {
      int sg = m0 + wr * 64 + mi * 16 + l15;
      int bb = sg >> 11, s = sg & 2047;
      short* orow = out + ((size_t)(bb * H_ + ntile) * S_ + s) * D_;
#pragma unroll
      for (int ni = 0; ni < 4; ++ni) {
        int d0 = wc * 64 + ni * 16 + l4 * 4;
        float4 bv = *(const float4*)(bias + n0 + d0);
        f32x4 t = acc[mi][ni];
        t[0] += bv.x; t[1] += bv.y; t[2] += bv.z; t[3] += bv.w;
        *(short4*)(orow + d0) = pack4(t);
      }
    }
  } else if (MODE == 1) {
#pragma unroll
    for (int mi = 0; mi < 4; ++mi) {
      int key = m0 + wr * 64 + mi * 16 + l15;
      int bb = key >> 11, k = key & 2047;
      size_t base = (size_t)(bb * H_ + ntile) * (S_ * D_) + (size_t)(k >> 6) * 8192
                  + ((k >> 4) & 3) * 4 * 512 + (k & 15) * 8;
#pragma unroll
      for (int ni = 0; ni < 4; ++ni) {
        int d0 = wc * 64 + ni * 16 + l4 * 4;
        float4 bv = *(const float4*)(bias + n0 + d0);
        f32x4 t = acc[mi][ni];
        t[0] += bv.x; t[1] += bv.y; t[2] += bv.z; t[3] += bv.w;
        size_t off = base + (size_t)(d0 >> 5) * 512 + ((d0 >> 3) & 3) * 128 + (d0 & 7);
        *(short4*)(out + off) = pack4(t);
      }
    }
  } else {
#pragma unroll
    for (int ni = 0; ni < 4; ++ni) {
      int d = wc * 64 + ni * 16 + l15;
      float bvs = bias[n0 + d];
#pragma unroll
      for (int mi = 0; mi < 4; ++mi) {
        int sg0 = m0 + wr * 64 + mi * 16 + l4 * 4;
        int bb = sg0 >> 11, s0 = sg0 & 2047;
        f32x4 t = acc[mi][ni];
        t[0] += bvs; t[1] += bvs; t[2] += bvs; t[3] += bvs;
        size_t off = (size_t)(bb * H_ + ntile) * (S_ * D_)
                   + (size_t)(s0 >> 6) * 8192
                   + (size_t)((d >> 4) * 2 + ((s0 >> 5) & 1)) * 512
                   + ((s0 >> 3) & 3) * 128 + (d & 15) * 8
                   + (s0 & 7);
        *(short4*)(out + off) = pack4(t);
      }
    }
  }
}

__global__ __launch_bounds__(256, 3) void proj3(
    const float* __restrict__ xq, const float* __restrict__ xk, const float* __restrict__ xv,
    const short* __restrict__ wtq, const short* __restrict__ wtk, const short* __restrict__ wtv,
    const float* __restrict__ bQ, const float* __restrict__ bK, const float* __restrict__ bV,
    short* __restrict__ Qp, short* __restrict__ Kf, short* __restrict__ Vf) {
  __shared__ short sA[16384];
  int work = (blockIdx.x & 7) * 192 + (blockIdx.x >> 3);
  int which = work >> 9;
  int t = work & 511;
  int mtile = t >> 3, ntile = t & 7;
  if (which == 0)      proj_tile<0>(xq, wtq, bQ, Qp, mtile, ntile, sA);
  else if (which == 1) proj_tile<1>(xk, wtk, bK, Kf, mtile, ntile, sA);
  else                 proj_tile<2>(xv, wtv, bV, Vf, mtile, ntile, sA);
}

// Flash-style attention with |score| softmax, NO max tracking.
// r10: BLOCK-SHARED LDS K/V (cuts L2 reads 2 GB -> 256 MB, the r8 pole) +
// r8's register-prefetch HSTEP structure now fed by ds_read_b128 (~120 cy,
// fully covered) instead of L2 (~600 cy). Q-tile 256 (8 waves x 32 q),
// grid 256 = 1 block/CU. K/V double-buffered via frag-linear dma16 (4/wave/tile);
// one __syncthreads per 64-key tile (vmcnt drain covered by 2 HSTEPs).
// Accumulation order per score / ls / o identical -> absmax 0.0004882812.
#define PSTR 72  // P row stride (shorts)

#define QK_H(KR)                                                               \
  _Pragma("unroll") for (int m = 0; m < 2; ++m) {                              \
    s0[m] = (f32x4){0.f, 0.f, 0.f, 0.f};                                       \
    s1[m] = (f32x4){0.f, 0.f, 0.f, 0.f};                                       \
    _Pragma("unroll") for (int st = 0; st < 4; ++st) {                         \
      s0[m] = __builtin_amdgcn_mfma_f32_16x16x32_bf16(KR[m * 4 + st], aq[0][st], s0[m], 0, 0, 0); \
      s1[m] = __builtin_amdgcn_mfma_f32_16x16x32_bf16(KR[m * 4 + st], aq[1][st], s1[m], 0, 0, 0); \
    }                                                                          \
  }

#define SM_H()                                                                 \
  _Pragma("unroll") for (int m = 0; m < 2; ++m) {                              \
    _Pragma("unroll") for (int r = 0; r < 4; ++r) {                            \
      float p = __builtin_amdgcn_exp2f(fabsf(s0[m][r]) * SC2);                 \
      ls0 += p;                                                                \
      s0[m][r] = p;                                                            \
    }                                                                          \
    *(short4*)(pw + l15 * PSTR + m * 16 + l4 * 4) = pack4(s0[m]);              \
  }                                                                            \
  ap0 = *(const bf16x8*)(pw + l15 * PSTR + l4 * 8);                            \
  _Pragma("unroll") for (int m = 0; m < 2; ++m) {                              \
    _Pragma("unroll") for (int r = 0; r < 4; ++r) {                            \
      float p = __builtin_amdgcn_exp2f(fabsf(s1[m][r]) * SC2);                 \
      ls1 += p;                                                                \
      s1[m][r] = p;                                                            \
    }                                                                          \
    *(short4*)(pw + l15 * PSTR + m * 16 + l4 * 4) = pack4(s1[m]);              \
  }                                                                            \
  ap1 = *(const bf16x8*)(pw + l15 * PSTR + l4 * 8);

#define PV_H()                                                                 \
  _Pragma("unroll") for (int t8 = 0; t8 < 8; ++t8) {                           \
    o0[t8] = __builtin_amdgcn_mfma_f32_16x16x32_bf16(ap0, bv[t8], o0[t8], 0, 0, 0); \
    o1[t8] = __builtin_amdgcn_mfma_f32_16x16x32_bf16(ap1, bv[t8], o1[t8], 0, 0, 0); \
  }

__global__ __launch_bounds__(512, 2) void attn(const short* __restrict__ Qp,
                                               const short* __restrict__ Kf,
                                               const short* __restrict__ Vf,
                                               float* __restrict__ out) {
  __shared__ short sK0[8192], sK1[8192];  // 16 KB per buffer, frag-linear
  __shared__ short sV0[8192], sV1[8192];
  __shared__ short sP[8 * 16 * PSTR];     // per-wave P region

  int tid = threadIdx.x;
  int lane = tid & 63, w = tid >> 6;      // w = 0..7
  // XCD swizzle: 4 bh per XCD -> K/V working set 4 MB = one L2.
  int xcd = blockIdx.x & 7;
  int idx = blockIdx.x >> 3;              // 0..31
  int bh  = xcd * 4 + (idx & 3);          // 0..31
  int qt  = idx >> 2;                     // 0..7 (q-tiles of 256)
  int q0  = qt * 256;
  int l15 = lane & 15, l4 = lane >> 4;

  const short* Qbase = Qp + (size_t)bh * S_ * D_;
  // frag-linear K/V: tile stride 8192 shorts, frag stride 512, lane slot 8.
  const short* kgs = Kf + (size_t)bh * S_ * D_ + 2 * w * 512 + lane * 8;
  const short* vgs = Vf + (size_t)bh * S_ * D_ + 2 * w * 512 + lane * 8;

  // stage tile 0 -> buf0 (wave w stages frags 2w, 2w+1 of K and V)
  dma16(kgs,       sK0 + 2 * w * 512);
  dma16(kgs + 512, sK0 + (2 * w + 1) * 512);
  dma16(vgs,       sV0 + 2 * w * 512);
  dma16(vgs + 512, sV0 + (2 * w + 1) * 512);

  // Q B-fragments for two 16-q groups (q = q0 + w*32 + g*16 + l15)
  bf16x8 aq[2][4];
#pragma unroll
  for (int g = 0; g < 2; ++g)
#pragma unroll
    for (int st = 0; st < 4; ++st)
      aq[g][st] = *(const bf16x8*)(Qbase + (q0 + w * 32 + g * 16 + l15) * D_ + l4 * 8 + 32 * st);

  f32x4 o0[8], o1[8];
#pragma unroll
  for (int t = 0; t < 8; ++t) {
    o0[t] = (f32x4){0.f, 0.f, 0.f, 0.f};
    o1[t] = (f32x4){0.f, 0.f, 0.f, 0.f};
  }
  float ls0 = 0.f, ls1 = 0.f;

  const float SC2 = 0.127530637f; // log2(e)/sqrt(128)
  short* pw = sP + w * 16 * PSTR;

  __syncthreads();  // tile 0 ready (all waves' DMA drained at barrier)

  for (int t = 0; t < 32; ++t) {
    const short* sKc = (t & 1) ? sK1 : sK0;
    const short* sVc = (t & 1) ? sV1 : sV0;
    if (t < 31) {
      short* sKn = (t & 1) ? sK0 : sK1;
      short* sVn = (t & 1) ? sV0 : sV1;
      const short* kn = kgs + (size_t)(t + 1) * 8192;
      const short* vn = vgs + (size_t)(t + 1) * 8192;
      dma16(kn,       sKn + 2 * w * 512);
      dma16(kn + 512, sKn + (2 * w + 1) * 512);
      dma16(vn,       sVn + 2 * w * 512);
      dma16(vn + 512, sVn + (2 * w + 1) * 512);
    }
    // K (both halves) + V half0: 24 ds_read_b128 issued upfront.
    bf16x8 kA[8], kB[8], bv[8];
#pragma unroll
    for (int j = 0; j < 8; ++j)
      kA[j] = *(const bf16x8*)(sKc + j * 512 + lane * 8);
#pragma unroll
    for (int j = 0; j < 8; ++j)
      kB[j] = *(const bf16x8*)(sKc + 4096 + j * 512 + lane * 8);
#pragma unroll
    for (int j = 0; j < 8; ++j)
      bv[j] = *(const bf16x8*)(sVc + (2 * j) * 512 + lane * 8);
    __builtin_amdgcn_sched_barrier(0);

    f32x4 s0[2], s1[2];
    bf16x8 ap0, ap1;
    // half 0
    __builtin_amdgcn_s_setprio(1);
    QK_H(kA);
    __builtin_amdgcn_s_setprio(0);
    SM_H();
    __builtin_amdgcn_s_setprio(1);
    PV_H();
    __builtin_amdgcn_s_setprio(0);
    // half 1
#pragma unroll
    for (int j = 0; j < 8; ++j)
      bv[j] = *(const bf16x8*)(sVc + (2 * j + 1) * 512 + lane * 8);
    __builtin_amdgcn_s_setprio(1);
    QK_H(kB);
    __builtin_amdgcn_s_setprio(0);
    SM_H();
    __builtin_amdgcn_s_setprio(1);
    PV_H();
    __builtin_amdgcn_s_setprio(0);
    __syncthreads();  // all waves done with buf[cur]; next-tile DMA drained
  }

  // final softmax denominators: per-lane partial sums -> quad reduce
  ls0 += __shfl_xor(ls0, 16);
  ls0 += __shfl_xor(ls0, 32);
  ls1 += __shfl_xor(ls1, 16);
  ls1 += __shfl_xor(ls1, 32);
  float inv0[4], inv1[4];
#pragma unroll
  for (int r = 0; r < 4; ++r) {
    inv0[r] = 1.f / __shfl(ls0, l4 * 4 + r);
    inv1[r] = 1.f / __shfl(ls1, l4 * 4 + r);
  }

  // epilogue: out[b, q, h*128 + dv] fp32
  int bb = bh >> 3, h = bh & 7;
#pragma unroll
  for (int t = 0; t < 8; ++t) {
#pragma unroll
    for (int r = 0; r < 4; ++r) {
      int qA = q0 + w * 32 + l4 * 4 + r;
      int qB = qA + 16;
      out[((size_t)(bb * S_ + qA)) * (H_ * D_) + h * D_ + t * 16 + l15] = o0[t][r] * inv0[r];
      out[((size_t)(bb * S_ + qB)) * (H_ * D_) + h * D_ + t * 16 + l15] = o1[t][r] * inv1[r];
    }
  }
}

extern "C" void kernel_launch(void* const* d_in, const int* in_sizes, int n_in,
                              void* d_out, int out_size, void* d_ws, size_t ws_size,
                              hipStream_t stream) {
  (void)in_sizes; (void)n_in; (void)out_size; (void)ws_size;
  const float* q  = (const float*)d_in[0];
  const float* k  = (const float*)d_in[1];
  const float* v  = (const float*)d_in[2];
  const float* WQ = (const float*)d_in[3];
  const float* bQ = (const float*)d_in[4];
  const float* WK = (const float*)d_in[5];
  const float* bK = (const float*)d_in[6];
  const float* WV = (const float*)d_in[7];
  const float* bV = (const float*)d_in[8];

  const int NW = D_ * H_ * D_;      // 131072 per weight
  const int NP = B_ * H_ * S_ * D_; // 8388608 per projected tensor

  short* ws  = (short*)d_ws;
  short* wtq = ws;
  short* wtk = wtq + NW;
  short* wtv = wtk + NW;
  short* Qp  = wtv + NW;
  short* Kf  = Qp + NP;
  short* Vf  = Kf + NP;

  prep<<<96, 256, 0, stream>>>(WQ, WK, WV, wtq, wtk, wtv);

  proj3<<<1536, 256, 0, stream>>>(q, k, v, wtq, wtk, wtv, bQ, bK, bV, Qp, Kf, Vf);

  attn<<<256, 512, 0, stream>>>(Qp, Kf, Vf, (float*)d_out);
}